// Round 3
// baseline (114.372 us; speedup 1.0000x reference)
//
#include <hip/hip_runtime.h>

#define HW (512 * 512)

typedef float vfloat4 __attribute__((ext_vector_type(4)));  // clang-native: OK for nontemporal builtins
typedef unsigned int vuint4 __attribute__((ext_vector_type(4)));

constexpr int CWP = 516;              // LDS row stride in words: 512 + 2 halo cols + 2 junk (keeps b128 16B-aligned)
constexpr float BWIDTH = 1.0f / 15.0f;
constexpr float DELTA = 3e-5f;        // guard >= ~2.5x the 1.2e-5 fast-path error bound

__global__ __launch_bounds__(256) void nectar_binning_kernel(
    const float* __restrict__ logits,      // [16,4,512,512]
    const float* __restrict__ val_freqs,   // [4,9,15]
    float* __restrict__ out)               // [16,4,512,512]
{
    // two software-pipelined 2-row panels per block; separate cls buffers (no WAR)
    __shared__ unsigned int cls0[4 * CWP];  // rows: halo-top, int0, int1, halo-bot
    __shared__ unsigned int cls1[4 * CWP];
    __shared__ float vf[540];

    // XCD-chunk swizzle (bijective, 2048 % 8 == 0): vertically-adjacent panel-pairs
    // land on the same XCD L2 -> shared halo rows are L2 hits.
    const unsigned int f = blockIdx.x;
    const unsigned int l = ((f & 7u) << 8) | (f >> 3);
    const int pp = (int)(l & 127u);        // 128 panel-pairs of 4 rows
    const int b  = (int)(l >> 7);          // 16 batches
    const int h0  = pp * 4;                // P0 = rows h0,h0+1; P1 = rows h0+2,h0+3
    const int tid = (int)threadIdx.x;

    for (int i = tid; i < 540; i += 256) vf[i] = val_freqs[i];
    if (tid < 4)      { cls0[tid * CWP] = 0u; cls0[tid * CWP + 513] = 0u; }
    else if (tid < 8) { cls1[(tid - 4) * CWP] = 0u; cls1[(tid - 4) * CWP + 513] = 0u; }

    const float* lb = logits + (size_t)b * 4 * HW;

    const int r = tid >> 7;            // row in panel, 0..1
    const int t = tid & 127;           // strip col
    const int w = 4 * t;
    const int base0 = ((h0 + r) << 9) + w;   // P0 interior strip
    const int base1 = base0 + 1024;          // P1 interior strip (2 rows down)

    // ---- issue P0 interior + P0 halo + P1 interior loads up front ----
    vfloat4 xa[4], hx[4], xb[4];  // [class] -> 4 px
    #pragma unroll
    for (int c = 0; c < 4; c++)
        xa[c] = *reinterpret_cast<const vfloat4*>(lb + (size_t)c * HW + base0);

    const int hh0 = r ? (h0 + 2) : (h0 - 1);     // P0 halo rows (h0+2 = P1 row 0: L1 hit later)
    const bool hv0 = (unsigned)hh0 < 512u;
    #pragma unroll
    for (int c = 0; c < 4; c++) { vfloat4 z = {0.f, 0.f, 0.f, 0.f}; hx[c] = z; }
    if (hv0) {
        const int hb = (hh0 << 9) + w;
        #pragma unroll
        for (int c = 0; c < 4; c++)
            hx[c] = *reinterpret_cast<const vfloat4*>(lb + (size_t)c * HW + hb);
    }
    #pragma unroll
    for (int c = 0; c < 4; c++)
        xb[c] = *reinterpret_cast<const vfloat4*>(lb + (size_t)c * HW + base1);

    // argmax -> one-hot nibble (first-index tie-break, bit-exact since R2)
    auto argnib = [](float x0, float x1, float x2, float x3) -> unsigned int {
        int c = 0; float best = x0;
        if (x1 > best) { best = x1; c = 1; }
        if (x2 > best) { best = x2; c = 2; }
        if (x3 > best) { best = x3; c = 3; }
        return 1u << (4 * c);
    };

    // per-pixel worker: argmax -> cls nibble to LDS, softmax -> 4 bins packed
    auto px_phase1 = [&](float x0, float x1, float x2, float x3,
                         unsigned int* clsbuf, int clsaddr) -> unsigned int {
        clsbuf[clsaddr] = argnib(x0, x1, x2, x3);

        float m = fmaxf(fmaxf(x0, x1), fmaxf(x2, x3));
        float t0 = x0 - m, t1 = x1 - m, t2 = x2 - m, t3 = x3 - m;
        // fast path: native exp + rcp; |q_fast - q_exact| <= ~1.2e-5 << DELTA
        float f0 = __expf(t0), f1 = __expf(t1), f2 = __expf(t2), f3 = __expf(t3);
        float sf = ((f0 + f1) + f2) + f3;
        float rs = __builtin_amdgcn_rcpf(sf);
        float q[4];
        q[0] = (f0 * rs) * 15.0f; q[1] = (f1 * rs) * 15.0f;
        q[2] = (f2 * rs) * 15.0f; q[3] = (f3 * rs) * 15.0f;
        bool slow = false;
        #pragma unroll
        for (int c2 = 0; c2 < 4; c2++) {
            float fr = q[c2] - floorf(q[c2]);
            slow |= (fr < DELTA) | (fr > 1.0f - DELTA);
        }
        if (slow) {  // exact ocml-exp + IEEE-divide chain (matches np: absmax 0 in R2/R3)
            float e0 = expf(t0), e1 = expf(t1), e2 = expf(t2), e3 = expf(t3);
            float s = ((e0 + e1) + e2) + e3;
            q[0] = (e0 / s) / BWIDTH; q[1] = (e1 / s) / BWIDTH;
            q[2] = (e2 / s) / BWIDTH; q[3] = (e3 / s) / BWIDTH;
        }
        unsigned int pb = 0;
        #pragma unroll
        for (int c2 = 0; c2 < 4; c2++) {
            int bin = (int)q[c2];
            bin = bin > 14 ? 14 : bin;
            pb |= (unsigned int)bin << (4 * c2);
        }
        return pb;
    };

    // phase 2: neighbor counts + gather + normalize + NT store (verified in R2)
    auto phase2 = [&](const unsigned int* clsbuf, const unsigned int* pbin, float* ob) {
        const unsigned int* p0 = &clsbuf[r * CWP + w];   // 16B-aligned: 2x ds_read_b128/row
        vuint4 ra[3], rb[3];
        #pragma unroll
        for (int k = 0; k < 3; k++) {
            ra[k] = *reinterpret_cast<const vuint4*>(p0 + k * CWP);
            rb[k] = *reinterpret_cast<const vuint4*>(p0 + k * CWP + 4);
        }
        unsigned int colsum[6], mid[6];
        #pragma unroll
        for (int k = 0; k < 6; k++) {
            unsigned int a0 = (k < 4) ? ra[0][k] : rb[0][k - 4];
            unsigned int a1 = (k < 4) ? ra[1][k] : rb[1][k - 4];
            unsigned int a2 = (k < 4) ? ra[2][k] : rb[2][k - 4];
            mid[k] = a1;
            colsum[k] = a0 + a1 + a2;
        }

        float res[4][4];  // [class][px]
        #pragma unroll
        for (int j = 0; j < 4; j++) {
            unsigned int pk = colsum[j] + colsum[j + 1] + colsum[j + 2] - mid[j + 1];
            unsigned int pb = pbin[j];
            float cs = 0.0f;
            float cal[4];
            #pragma unroll
            for (int c = 0; c < 4; c++) {
                int cnt = (int)((pk >> (4 * c)) & 0xFu);   // [0,8]
                int bin = (int)((pb >> (4 * c)) & 0xFu);   // [0,14]
                float v = vf[c * 135 + cnt * 15 + bin];
                cal[c] = v;
                cs += v;                                   // ref class order
            }
            if (cs == 0.0f) cs = 1.0f;
            float inv = __builtin_amdgcn_rcpf(cs);         // tolerance 1.97e-2 >> 1 ULP
            #pragma unroll
            for (int c = 0; c < 4; c++) res[c][j] = cal[c] * inv;
        }
        #pragma unroll
        for (int c = 0; c < 4; c++) {
            vfloat4 v;
            v.x = res[c][0]; v.y = res[c][1]; v.z = res[c][2]; v.w = res[c][3];
            __builtin_nontemporal_store(v, reinterpret_cast<vfloat4*>(ob + (size_t)c * HW));
        }
    };

    // ---- P0 compute (xa/hx in flight longest) ----
    const int ia = (r + 1) * CWP + 1 + w;    // interior cls addr base
    const int ha = (r ? 3 : 0) * CWP + 1 + w; // halo cls addr base
    unsigned int pbin0[4];
    #pragma unroll
    for (int j = 0; j < 4; j++)
        pbin0[j] = px_phase1(xa[0][j], xa[1][j], xa[2][j], xa[3][j], cls0, ia + j);
    #pragma unroll
    for (int j = 0; j < 4; j++)
        cls0[ha + j] = hv0 ? argnib(hx[0][j], hx[1][j], hx[2][j], hx[3][j]) : 0u;

    // issue P1 halo loads (hx registers just died; overlap barrier + P1 softmax)
    const int hh1 = r ? (h0 + 4) : (h0 + 1);     // h0+1 = P0 row 1: L1 hit
    const bool hv1 = (unsigned)hh1 < 512u;
    vfloat4 hy[4];
    #pragma unroll
    for (int c = 0; c < 4; c++) { vfloat4 z = {0.f, 0.f, 0.f, 0.f}; hy[c] = z; }
    if (hv1) {
        const int hb = (hh1 << 9) + w;
        #pragma unroll
        for (int c = 0; c < 4; c++)
            hy[c] = *reinterpret_cast<const vfloat4*>(lb + (size_t)c * HW + hb);
    }
    __syncthreads();   // cls0 complete

    // ---- P1 compute (xb has been in flight through all of P0's compute) ----
    unsigned int pbin1[4];
    #pragma unroll
    for (int j = 0; j < 4; j++)
        pbin1[j] = px_phase1(xb[0][j], xb[1][j], xb[2][j], xb[3][j], cls1, ia + j);
    #pragma unroll
    for (int j = 0; j < 4; j++)
        cls1[ha + j] = hv1 ? argnib(hy[0][j], hy[1][j], hy[2][j], hy[3][j]) : 0u;

    // ---- P0 epilogue (stores flow while other waves still load/compute) ----
    float* obase = out + (size_t)b * 4 * HW;
    phase2(cls0, pbin0, obase + base0);
    __syncthreads();   // cls1 complete
    phase2(cls1, pbin1, obase + base1);
}

extern "C" void kernel_launch(void* const* d_in, const int* in_sizes, int n_in,
                              void* d_out, int out_size, void* d_ws, size_t ws_size,
                              hipStream_t stream) {
    const float* logits    = (const float*)d_in[0];
    const float* val_freqs = (const float*)d_in[1];
    float* out             = (float*)d_out;

    dim3 block(256, 1, 1);
    dim3 grid(2048, 1, 1);   // 128 panel-pairs x 16 batches, XCD-swizzled in-kernel
    hipLaunchKernelGGL(nectar_binning_kernel, grid, block, 0, stream,
                       logits, val_freqs, out);
}